// Round 11
// baseline (308.736 us; speedup 1.0000x reference)
//
#include <hip/hip_runtime.h>
#include <hip/hip_bf16.h>

// ---------------------------------------------------------------------------
// T5 MHA: B=2, S=2048, D_FF=1024, H=16, DK=64, INNER=1024
// Precision: q carried hi+lo (2-chain QK vs k_hi); W's split for projections.
// Attn v9: q=32/wave (halves LDS reads/MFMA vs v8), 256 thr / 4 waves,
//   2 blocks/CU under launch_bounds(256,2) (VGPR cap 256 -> no spill; the
//   R8/R9 spills were the (512,4) 128-cap). Stride-76 LDS (0 conflicts,
//   R10-proven). Double-buffered K/V -> ONE barrier per chunk. Depth-2
//   global prefetch. __builtin_amdgcn_exp2f (R10's exp2f libm call was the
//   +12us VALU regression). defer-max, cvt_pk P-pack, mask reg prefetch.
// ---------------------------------------------------------------------------

typedef __attribute__((ext_vector_type(8))) short short8_t;   // 8 bf16 (4 VGPR)
typedef __attribute__((ext_vector_type(4))) short short4_t;
typedef __attribute__((ext_vector_type(4))) float f32x4_t;

#define SEQ 2048
#define HEADS 16
#define DK 64
#define DFF 1024
#define LOG2E 1.44269504088896340736f
#define LSTR 76   // LDS row stride (bf16): 38 dwords == 6 mod 32 banks

__device__ __forceinline__ unsigned short f32_to_bf16(float f) {
  unsigned int u = __float_as_uint(f);
  u += 0x7FFFu + ((u >> 16) & 1u);   // round-to-nearest-even
  return (unsigned short)(u >> 16);
}
__device__ __forceinline__ float bf16_to_f32(unsigned short h) {
  return __uint_as_float(((unsigned int)h) << 16);
}
__device__ __forceinline__ unsigned int cvt_pk_bf16(float a, float b) {
  unsigned int r;
  asm("v_cvt_pk_bf16_f32 %0, %1, %2" : "=v"(r) : "v"(a), "v"(b));
  return r;
}
__device__ __forceinline__ float fexp2(float x) {
  return __builtin_amdgcn_exp2f(x);   // raw v_exp_f32 (2^x)
}

__device__ __forceinline__ void gload_lds16(const void* g, void* l) {
  __builtin_amdgcn_global_load_lds(
      (__attribute__((address_space(1))) void*)(g),
      (__attribute__((address_space(3))) void*)(l), 16, 0, 0);
}

// ---------------------------------------------------------------------------
// cvt_x: q/k/v fp32 -> bf16, one dispatch
// ---------------------------------------------------------------------------
__global__ void cvt_x_kernel(const float* __restrict__ q,
                             const float* __restrict__ k,
                             const float* __restrict__ v,
                             short* __restrict__ dst, int n) {
  const float* src = (blockIdx.y == 0) ? q : (blockIdx.y == 1) ? k : v;
  short* out = dst + (size_t)blockIdx.y * n;
  int i = (blockIdx.x * 256 + threadIdx.x) * 4;
  if (i >= n) return;
  float4 f = *(const float4*)(src + i);
  short4_t s;
  s[0] = (short)f32_to_bf16(f.x);
  s[1] = (short)f32_to_bf16(f.y);
  s[2] = (short)f32_to_bf16(f.z);
  s[3] = (short)f32_to_bf16(f.w);
  *(short4_t*)(out + i) = s;
}

// ---------------------------------------------------------------------------
// cvt_w: y<3 -> split W[y] into hi+lo pair; y==3 -> plain Wo
// ---------------------------------------------------------------------------
__global__ void cvt_w_kernel(const float* __restrict__ Wq,
                             const float* __restrict__ Wk,
                             const float* __restrict__ Wv,
                             const float* __restrict__ Wo,
                             short* __restrict__ wbase, int n) {
  int y = blockIdx.y;
  const float* src = (y == 0) ? Wq : (y == 1) ? Wk : (y == 2) ? Wv : Wo;
  int i = (blockIdx.x * 256 + threadIdx.x) * 4;
  if (i >= n) return;
  float4 f = *(const float4*)(src + i);
  float ff[4] = {f.x, f.y, f.z, f.w};
  if (y < 3) {
    short* hi = wbase + (size_t)(2 * y) * n;
    short* lo = wbase + (size_t)(2 * y + 1) * n;
    short4_t h, l;
#pragma unroll
    for (int j = 0; j < 4; ++j) {
      unsigned short hh = f32_to_bf16(ff[j]);
      h[j] = (short)hh;
      l[j] = (short)f32_to_bf16(ff[j] - bf16_to_f32(hh));
    }
    *(short4_t*)(hi + i) = h;
    *(short4_t*)(lo + i) = l;
  } else {
    short* out = wbase + (size_t)6 * n;
    short4_t s;
#pragma unroll
    for (int j = 0; j < 4; ++j) s[j] = (short)f32_to_bf16(ff[j]);
    *(short4_t*)(out + i) = s;
  }
}

// ---------------------------------------------------------------------------
// Projection GEMM: C[M,1024] = A[M,K] @ (Bh+Bl)[1024,K]^T, 2 MFMA chains.
// Tile 128M x 64N. EPI 0: Q hi+lo head-split, PRE-SCALED by log2e.
// EPI 1: K hi head-split. EPI 2: V hi TRANSPOSED [B,H,64,S].
// ---------------------------------------------------------------------------
template <int EPI>
__global__ __launch_bounds__(256, 2) void gemm_proj(
    const short* __restrict__ A, const short* __restrict__ Bh,
    const short* __restrict__ Bl, short* __restrict__ Ohi,
    short* __restrict__ Olo, int M, int K) {
  __shared__ short As[128 * 32];
  __shared__ short Bsh[64 * 32];
  __shared__ short Bsl[64 * 32];

  const int tid = threadIdx.x;
  const int w = tid >> 6, l = tid & 63, g = l >> 4, c = l & 15;
  const int wr = w >> 1, wc = w & 1;
  const int m0 = blockIdx.y * 128, n0 = blockIdx.x * 64;

  f32x4_t acc[4][2] = {};

  for (int k0 = 0; k0 < K; k0 += 32) {
#pragma unroll
    for (int j = 0; j < 2; ++j) {
      int e = (w * 2 + j) * 512 + l * 8;
      int r = e >> 5, cc = e & 31;
      gload_lds16(A + (size_t)(m0 + r) * K + k0 + cc, &As[(w * 2 + j) * 512]);
    }
    {
      int e = w * 512 + l * 8;
      int r = e >> 5, cc = e & 31;
      gload_lds16(Bh + (size_t)(n0 + r) * K + k0 + cc, &Bsh[w * 512]);
      gload_lds16(Bl + (size_t)(n0 + r) * K + k0 + cc, &Bsl[w * 512]);
    }
    __syncthreads();

    short8_t a[4], bh[2], bl[2];
#pragma unroll
    for (int mi = 0; mi < 4; ++mi)
      a[mi] = *(const short8_t*)(&As[(wr * 64 + mi * 16 + c) * 32 + g * 8]);
#pragma unroll
    for (int ni = 0; ni < 2; ++ni) {
      bh[ni] = *(const short8_t*)(&Bsh[(wc * 32 + ni * 16 + c) * 32 + g * 8]);
      bl[ni] = *(const short8_t*)(&Bsl[(wc * 32 + ni * 16 + c) * 32 + g * 8]);
    }
#pragma unroll
    for (int mi = 0; mi < 4; ++mi)
#pragma unroll
      for (int ni = 0; ni < 2; ++ni) {
        acc[mi][ni] = __builtin_amdgcn_mfma_f32_16x16x32_bf16(
            a[mi], bh[ni], acc[mi][ni], 0, 0, 0);
        acc[mi][ni] = __builtin_amdgcn_mfma_f32_16x16x32_bf16(
            a[mi], bl[ni], acc[mi][ni], 0, 0, 0);
      }
    __syncthreads();
  }

#pragma unroll
  for (int mi = 0; mi < 4; ++mi) {
#pragma unroll
    for (int ni = 0; ni < 2; ++ni) {
      int col = n0 + wc * 32 + ni * 16 + c;
      int hh = col >> 6, dd = col & 63;
      if (EPI == 2) {
        int row0 = m0 + wr * 64 + mi * 16 + g * 4;
        int bb = row0 >> 11, ss0 = row0 & 2047;
        short4_t s4;
#pragma unroll
        for (int j = 0; j < 4; ++j) s4[j] = (short)f32_to_bf16(acc[mi][ni][j]);
        *(short4_t*)(&Ohi[(((size_t)bb * HEADS + hh) * DK + dd) * SEQ + ss0]) = s4;
      } else {
#pragma unroll
        for (int j = 0; j < 4; ++j) {
          int row = m0 + wr * 64 + mi * 16 + g * 4 + j;
          int bb = row >> 11, ss = row & 2047;
          size_t idx = (((size_t)bb * HEADS + hh) * SEQ + ss) * DK + dd;
          float x = acc[mi][ni][j];
          if (EPI == 0) x *= LOG2E;   // fold log2e into Q for exp2 softmax
          unsigned short xh = f32_to_bf16(x);
          Ohi[idx] = (short)xh;
          if (EPI == 0)
            Olo[idx] = (short)f32_to_bf16(x - bf16_to_f32(xh));
        }
      }
    }
  }
}

// ---------------------------------------------------------------------------
// Output GEMM: O[M,1024] fp32 = A[M,K] @ Bw[1024,K]^T, plain bf16, 1 chain.
// ---------------------------------------------------------------------------
__global__ __launch_bounds__(256, 2) void gemm_out(
    const short* __restrict__ A, const short* __restrict__ Bw,
    float* __restrict__ O, int M, int K) {
  __shared__ short As[128 * 32];
  __shared__ short Bs[64 * 32];

  const int tid = threadIdx.x;
  const int w = tid >> 6, l = tid & 63, g = l >> 4, c = l & 15;
  const int wr = w >> 1, wc = w & 1;
  const int m0 = blockIdx.y * 128, n0 = blockIdx.x * 64;

  f32x4_t acc[4][2] = {};

  for (int k0 = 0; k0 < K; k0 += 32) {
#pragma unroll
    for (int j = 0; j < 2; ++j) {
      int e = (w * 2 + j) * 512 + l * 8;
      int r = e >> 5, cc = e & 31;
      gload_lds16(A + (size_t)(m0 + r) * K + k0 + cc, &As[(w * 2 + j) * 512]);
    }
    {
      int e = w * 512 + l * 8;
      int r = e >> 5, cc = e & 31;
      gload_lds16(Bw + (size_t)(n0 + r) * K + k0 + cc, &Bs[w * 512]);
    }
    __syncthreads();

    short8_t a[4], b[2];
#pragma unroll
    for (int mi = 0; mi < 4; ++mi)
      a[mi] = *(const short8_t*)(&As[(wr * 64 + mi * 16 + c) * 32 + g * 8]);
#pragma unroll
    for (int ni = 0; ni < 2; ++ni)
      b[ni] = *(const short8_t*)(&Bs[(wc * 32 + ni * 16 + c) * 32 + g * 8]);
#pragma unroll
    for (int mi = 0; mi < 4; ++mi)
#pragma unroll
      for (int ni = 0; ni < 2; ++ni)
        acc[mi][ni] = __builtin_amdgcn_mfma_f32_16x16x32_bf16(
            a[mi], b[ni], acc[mi][ni], 0, 0, 0);
    __syncthreads();
  }

#pragma unroll
  for (int mi = 0; mi < 4; ++mi)
#pragma unroll
    for (int ni = 0; ni < 2; ++ni) {
      int col = n0 + wc * 32 + ni * 16 + c;
#pragma unroll
      for (int j = 0; j < 4; ++j) {
        int row = m0 + wr * 64 + mi * 16 + g * 4 + j;
        O[(size_t)row * DFF + col] = acc[mi][ni][j];
      }
    }
}

// ---------------------------------------------------------------------------
// Flash attention v9. Grid (B*H, S/128), 256 thr = 4 waves x 32 q-rows.
// Double-buffered K/V LDS, one barrier per chunk, depth-2 global prefetch.
// S^T: mfma(A=K_hi rows kv, B=Q rows q). PV: O^T = mfma(A=V^T, B=P).
// LDS map (shorts): K[2][64*76]@0, V[2][64*76]@9728, Ps[4][32*76]@19456.
// ---------------------------------------------------------------------------
__global__ __launch_bounds__(256, 2) void attn_kernel(
    const short* __restrict__ qhh, const short* __restrict__ qhl,
    const short* __restrict__ khh, const short* __restrict__ vt,
    const float* __restrict__ mask, short* __restrict__ ctx) {
  const int bh = blockIdx.x;
  const int b = bh >> 4;
  const int h = bh & 15;
  const int qt = blockIdx.y;
  const int tid = threadIdx.x;
  const int w = tid >> 6, l = tid & 63, g = l >> 4, c = l & 15;

  __shared__ short smem[29184];          // 58368 B
  short* psw = &smem[19456 + w * 2432];  // per-wave P [32][76]

  const int qrow0 = qt * 128 + w * 32;
  const short* Qbh = qhh + ((size_t)bh * SEQ + qrow0) * DK;
  const short* Qbl = qhl + ((size_t)bh * SEQ + qrow0) * DK;
  const short* Kbh = khh + (size_t)bh * SEQ * DK;
  const short* Vb  = vt  + (size_t)bh * DK * SEQ;           // [64][SEQ]
  const float* M0  = mask + (size_t)b * SEQ * SEQ + (size_t)(qrow0 + c) * SEQ;

  // staging: each thread 16 contiguous shorts per buffer
  const int srow = tid >> 2;            // 0..63
  const int scol = (tid & 3) * 16;      // 0,16,32,48
  const int sofs = srow * LSTR + scol;

  // Q frags (B-operand): lane c holds Q row q=mi*16+c, k = ks*32+g*8
  short8_t qfh[2][2], qfl[2][2];
#pragma unroll
  for (int mi = 0; mi < 2; ++mi)
#pragma unroll
    for (int ks = 0; ks < 2; ++ks) {
      qfh[mi][ks] = *(const short8_t*)(Qbh + (size_t)(mi * 16 + c) * DK + ks * 32 + g * 8);
      qfl[mi][ks] = *(const short8_t*)(Qbl + (size_t)(mi * 16 + c) * DK + ks * 32 + g * 8);
    }

  // prologue: chunk0 -> LDS buf0; chunk1 -> regs; chunk0 mask -> regs
  short8_t rk0 = *(const short8_t*)(Kbh + (size_t)srow * DK + scol);
  short8_t rk1 = *(const short8_t*)(Kbh + (size_t)srow * DK + scol + 8);
  short8_t rv0 = *(const short8_t*)(Vb + (size_t)srow * SEQ + scol);
  short8_t rv1 = *(const short8_t*)(Vb + (size_t)srow * SEQ + scol + 8);
  *(short8_t*)(&smem[sofs]) = rk0;
  *(short8_t*)(&smem[sofs + 8]) = rk1;
  *(short8_t*)(&smem[9728 + sofs]) = rv0;
  *(short8_t*)(&smem[9728 + sofs + 8]) = rv1;
  rk0 = *(const short8_t*)(Kbh + (size_t)(64 + srow) * DK + scol);
  rk1 = *(const short8_t*)(Kbh + (size_t)(64 + srow) * DK + scol + 8);
  rv0 = *(const short8_t*)(Vb + (size_t)srow * SEQ + 64 + scol);
  rv1 = *(const short8_t*)(Vb + (size_t)srow * SEQ + 64 + scol + 8);

  float4 mpre[2][4];
#pragma unroll
  for (int mi = 0; mi < 2; ++mi)
#pragma unroll
    for (int ni = 0; ni < 4; ++ni)
      mpre[mi][ni] = *(const float4*)(M0 + (size_t)(mi * 16) * SEQ + ni * 16 + g * 4);

  __syncthreads();   // buf0 visible

  f32x4_t o[4][2] = {};          // o[di][mi]: O^T rows d=di*16+g*4+j, col q
  float mrun[2] = {-1e30f, -1e30f};
  float lrun[2] = {0.f, 0.f};

  int cur = 0;
  for (int t = 0; t < 32; ++t) {
    const short* Ks = &smem[cur * 4864];
    const short* Vs = &smem[9728 + cur * 4864];

    // ---- S^T = K_hi (Q_hi + Q_lo)^T : 2 chains ----
    f32x4_t sa[4][2] = {};       // sa[ni][mi]: rows kv=ni*16+g*4+j, col q
    __builtin_amdgcn_s_setprio(1);
#pragma unroll
    for (int ks = 0; ks < 2; ++ks) {
      short8_t ah[4];
#pragma unroll
      for (int ni = 0; ni < 4; ++ni)
        ah[ni] = *(const short8_t*)(&Ks[(ni * 16 + c) * LSTR + ks * 32 + g * 8]);
#pragma unroll
      for (int ni = 0; ni < 4; ++ni)
#pragma unroll
        for (int mi = 0; mi < 2; ++mi) {
          sa[ni][mi] = __builtin_amdgcn_mfma_f32_16x16x32_bf16(
              ah[ni], qfh[mi][ks], sa[ni][mi], 0, 0, 0);
          sa[ni][mi] = __builtin_amdgcn_mfma_f32_16x16x32_bf16(
              ah[ni], qfl[mi][ks], sa[ni][mi], 0, 0, 0);
        }
    }
    __builtin_amdgcn_s_setprio(0);

    // ---- + mask * log2e from prefetched regs; then prefetch t+1 ----
#pragma unroll
    for (int mi = 0; mi < 2; ++mi)
#pragma unroll
      for (int ni = 0; ni < 4; ++ni) {
        sa[ni][mi][0] = fmaf(mpre[mi][ni].x, LOG2E, sa[ni][mi][0]);
        sa[ni][mi][1] = fmaf(mpre[mi][ni].y, LOG2E, sa[ni][mi][1]);
        sa[ni][mi][2] = fmaf(mpre[mi][ni].z, LOG2E, sa[ni][mi][2]);
        sa[ni][mi][3] = fmaf(mpre[mi][ni].w, LOG2E, sa[ni][mi][3]);
      }
    if (t + 1 < 32) {
      int kvn = (t + 1) * 64;
#pragma unroll
      for (int mi = 0; mi < 2; ++mi)
#pragma unroll
        for (int ni = 0; ni < 4; ++ni)
          mpre[mi][ni] = *(const float4*)(M0 + (size_t)(mi * 16) * SEQ + kvn + ni * 16 + g * 4);
    }

    // ---- online softmax (log2 space), defer-max THR=8, per mi ----
#pragma unroll
    for (int mi = 0; mi < 2; ++mi) {
      float tmx = sa[0][mi][0];
#pragma unroll
      for (int ni = 0; ni < 4; ++ni)
#pragma unroll
        for (int j = 0; j < 4; ++j) tmx = fmaxf(tmx, sa[ni][mi][j]);
      tmx = fmaxf(tmx, __shfl_xor(tmx, 16));
      tmx = fmaxf(tmx, __shfl_xor(tmx, 32));
      if (!__all(tmx - mrun[mi] <= 8.f)) {
        float mnew = fmaxf(mrun[mi], tmx);
        float sc = fexp2(mrun[mi] - mnew);
        mrun[mi] = mnew;
        lrun[mi] *= sc;
#pragma unroll
        for (int di = 0; di < 4; ++di)
#pragma unroll
          for (int j = 0; j < 4; ++j) o[di][mi][j] *= sc;
      }
      float psum = 0.f;
#pragma unroll
      for (int ni = 0; ni < 4; ++ni) {
        float p0 = fexp2(sa[ni][mi][0] - mrun[mi]);
        float p1 = fexp2(sa[ni][mi][1] - mrun[mi]);
        float p2 = fexp2(sa[ni][mi][2] - mrun[mi]);
        float p3 = fexp2(sa[ni][mi][3] - mrun[mi]);
        psum += (p0 + p1) + (p2 + p3);
        unsigned int u0 = cvt_pk_bf16(p0, p1);
        unsigned int u1 = cvt_pk_bf16(p2, p3);
        unsigned long long pu = ((unsigned long long)u1 << 32) | u0;
        *(unsigned long long*)(&psw[(mi * 16 + c) * LSTR + ni * 16 + g * 4]) = pu;
      }
      lrun[mi] += psum;
    }

    // ---- O^T += V^T P^T ----
    __builtin_amdgcn_s_setprio(1);
#pragma unroll
    for (int ks = 0; ks < 2; ++ks) {
      short8_t pb[2];
#pragma unroll
      for (int mi = 0; mi < 2; ++mi)
        pb[mi] = *(const short8_t*)(&psw[(mi * 16 + c) * LSTR + ks * 32 + g * 8]);
#pragma unroll
      for (int di = 0; di < 4; ++di) {
        short8_t av = *(const short8_t*)(&Vs[(di * 16 + c) * LSTR + ks * 32 + g * 8]);
#pragma unroll
        for (int mi = 0; mi < 2; ++mi)
          o[di][mi] = __builtin_amdgcn_mfma_f32_16x16x32_bf16(
              av, pb[mi], o[di][mi], 0, 0, 0);
      }
    }
    __builtin_amdgcn_s_setprio(0);

    // ---- stage chunk t+1 into buf[cur^1]; prefetch chunk t+2 ----
    if (t + 1 < 32) {
      short* Kd = &smem[(cur ^ 1) * 4864];
      short* Vd = &smem[9728 + (cur ^ 1) * 4864];
      *(short8_t*)(&Kd[sofs]) = rk0;
      *(short8_t*)(&Kd[sofs + 8]) = rk1;
      *(short8_t*)(&Vd[sofs]) = rv0;
      *(short8_t*)(&Vd[sofs + 8]) = rv1;
      if (t + 2 < 32) {
        int kvn = (t + 2) * 64;
        rk0 = *(const short8_t*)(Kbh + (size_t)(kvn + srow) * DK + scol);
        rk1 = *(const short8_t*)(Kbh + (size_t)(kvn + srow) * DK + scol + 8);
        rv0 = *(const short8_t*)(Vb + (size_t)srow * SEQ + kvn + scol);
        rv1 = *(const short8_t*)(Vb + (size_t)srow * SEQ + kvn + scol + 8);
      }
    }
    __syncthreads();   // buf[cur^1] ready; all reads of buf[cur] done
    cur ^= 1;
  }

  // ---- finalize: reduce l across g-groups, normalize, short4 stores ----
  float inv[2];
#pragma unroll
  for (int mi = 0; mi < 2; ++mi) {
    float s = lrun[mi];
    s += __shfl_xor(s, 16);
    s += __shfl_xor(s, 32);
    inv[mi] = 1.f / s;
  }
  short* Cb = ctx + ((size_t)b * SEQ + qrow0) * DFF + h * DK;
#pragma unroll
  for (int mi = 0; mi < 2; ++mi)
#pragma unroll
    for (int di = 0; di < 4; ++di) {
      short4_t s4;
#pragma unroll
      for (int j = 0; j < 4; ++j)
        s4[j] = (short)f32_to_bf16(o[di][mi][j] * inv[mi]);
      *(short4_t*)(Cb + (size_t)(mi * 16 + c) * DFF + di * 16 + g * 4) = s4;
    }
}

// ---------------------------------------------------------------------------
extern "C" void kernel_launch(void* const* d_in, const int* in_sizes, int n_in,
                              void* d_out, int out_size, void* d_ws, size_t ws_size,
                              hipStream_t stream) {
  const float* q    = (const float*)d_in[0];
  const float* k    = (const float*)d_in[1];
  const float* v    = (const float*)d_in[2];
  const float* mask = (const float*)d_in[3];
  const float* Wq   = (const float*)d_in[4];
  const float* Wk   = (const float*)d_in[5];
  const float* Wv   = (const float*)d_in[6];
  const float* Wo   = (const float*)d_in[7];
  float* out = (float*)d_out;

  const size_t NQ = 4194304;   // 4096*1024
  const size_t NW = 1048576;   // 1024*1024
  short* ws   = (short*)d_ws;
  short* qbf  = ws;            // A0; reused as kh_h after Q-proj
  short* kbf  = ws + NQ;       // A1; reused as vtp after K-proj
  short* vbf  = ws + 2 * NQ;   // A2; reused as ctx after V-proj
  short* qh_h = ws + 3 * NQ;
  short* qh_l = ws + 4 * NQ;
  short* wbase = ws + 5 * NQ;  // [wq_h wq_l wk_h wk_l wv_h wv_l wob], NW each
  short* wq_h = wbase;
  short* wq_l = wbase + NW;
  short* wk_h = wbase + 2 * NW;
  short* wk_l = wbase + 3 * NW;
  short* wv_h = wbase + 4 * NW;
  short* wv_l = wbase + 5 * NW;
  short* wob  = wbase + 6 * NW;   // total 5*NQ + 7*NW = 56.6 MB

  short* kh_h = qbf;   // aliases (stream-ordered, safe)
  short* vtp  = kbf;   // V transposed [B,H,64,S]
  short* ctx  = vbf;

  cvt_x_kernel<<<dim3(4096, 3), 256, 0, stream>>>(q, k, v, ws, (int)NQ);
  cvt_w_kernel<<<dim3(1024, 4), 256, 0, stream>>>(Wq, Wk, Wv, Wo, wbase, (int)NW);

  dim3 gg(16, 32);   // N/64, M/128
  gemm_proj<0><<<gg, 256, 0, stream>>>(qbf, wq_h, wq_l, qh_h, qh_l, 4096, 1024);
  gemm_proj<1><<<gg, 256, 0, stream>>>(kbf, wk_h, wk_l, kh_h, nullptr, 4096, 1024);
  gemm_proj<2><<<gg, 256, 0, stream>>>(vbf, wv_h, wv_l, vtp, nullptr, 4096, 1024);

  attn_kernel<<<dim3(32, 16), 256, 0, stream>>>(qh_h, qh_l, kh_h, vtp, mask, ctx);

  gemm_out<<<gg, 256, 0, stream>>>(ctx, wob, out, 4096, 1024);
}

// Round 12
// 308.135 us; speedup vs baseline: 1.0020x; 1.0020x over previous
//
#include <hip/hip_runtime.h>
#include <hip/hip_bf16.h>

// ---------------------------------------------------------------------------
// T5 MHA: B=2, S=2048, D_FF=1024, H=16, DK=64, INNER=1024
// Precision: q carried hi+lo (2-chain QK vs k_hi); W's split for projections.
// Attn v10 = v9 with the staging block moved to the TOP of the loop:
//   R11 issued prefetch loads immediately before __syncthreads(), whose
//   vmcnt(0) drain killed all latency cover (205us, MfmaUtil 10%).
//   Now: [barrier] -> ds_write chunk t+1 (regs from last iter, full-iter
//   cover) -> issue t+2 loads (drain at END-of-t barrier, full compute
//   cover) -> compute(t). Single barrier/chunk, dbuf K/V, stride-76 (0
//   conflicts), fexp2, defer-max, cvt_pk, q=32/wave.
// ---------------------------------------------------------------------------

typedef __attribute__((ext_vector_type(8))) short short8_t;   // 8 bf16 (4 VGPR)
typedef __attribute__((ext_vector_type(4))) short short4_t;
typedef __attribute__((ext_vector_type(4))) float f32x4_t;

#define SEQ 2048
#define HEADS 16
#define DK 64
#define DFF 1024
#define LOG2E 1.44269504088896340736f
#define LSTR 76   // LDS row stride (bf16): 38 dwords == 6 mod 32 banks

__device__ __forceinline__ unsigned short f32_to_bf16(float f) {
  unsigned int u = __float_as_uint(f);
  u += 0x7FFFu + ((u >> 16) & 1u);   // round-to-nearest-even
  return (unsigned short)(u >> 16);
}
__device__ __forceinline__ float bf16_to_f32(unsigned short h) {
  return __uint_as_float(((unsigned int)h) << 16);
}
__device__ __forceinline__ unsigned int cvt_pk_bf16(float a, float b) {
  unsigned int r;
  asm("v_cvt_pk_bf16_f32 %0, %1, %2" : "=v"(r) : "v"(a), "v"(b));
  return r;
}
__device__ __forceinline__ float fexp2(float x) {
  return __builtin_amdgcn_exp2f(x);   // raw v_exp_f32 (2^x)
}

__device__ __forceinline__ void gload_lds16(const void* g, void* l) {
  __builtin_amdgcn_global_load_lds(
      (__attribute__((address_space(1))) void*)(g),
      (__attribute__((address_space(3))) void*)(l), 16, 0, 0);
}

// ---------------------------------------------------------------------------
// cvt_x: q/k/v fp32 -> bf16, one dispatch
// ---------------------------------------------------------------------------
__global__ void cvt_x_kernel(const float* __restrict__ q,
                             const float* __restrict__ k,
                             const float* __restrict__ v,
                             short* __restrict__ dst, int n) {
  const float* src = (blockIdx.y == 0) ? q : (blockIdx.y == 1) ? k : v;
  short* out = dst + (size_t)blockIdx.y * n;
  int i = (blockIdx.x * 256 + threadIdx.x) * 4;
  if (i >= n) return;
  float4 f = *(const float4*)(src + i);
  short4_t s;
  s[0] = (short)f32_to_bf16(f.x);
  s[1] = (short)f32_to_bf16(f.y);
  s[2] = (short)f32_to_bf16(f.z);
  s[3] = (short)f32_to_bf16(f.w);
  *(short4_t*)(out + i) = s;
}

// ---------------------------------------------------------------------------
// cvt_w: y<3 -> split W[y] into hi+lo pair; y==3 -> plain Wo
// ---------------------------------------------------------------------------
__global__ void cvt_w_kernel(const float* __restrict__ Wq,
                             const float* __restrict__ Wk,
                             const float* __restrict__ Wv,
                             const float* __restrict__ Wo,
                             short* __restrict__ wbase, int n) {
  int y = blockIdx.y;
  const float* src = (y == 0) ? Wq : (y == 1) ? Wk : (y == 2) ? Wv : Wo;
  int i = (blockIdx.x * 256 + threadIdx.x) * 4;
  if (i >= n) return;
  float4 f = *(const float4*)(src + i);
  float ff[4] = {f.x, f.y, f.z, f.w};
  if (y < 3) {
    short* hi = wbase + (size_t)(2 * y) * n;
    short* lo = wbase + (size_t)(2 * y + 1) * n;
    short4_t h, l;
#pragma unroll
    for (int j = 0; j < 4; ++j) {
      unsigned short hh = f32_to_bf16(ff[j]);
      h[j] = (short)hh;
      l[j] = (short)f32_to_bf16(ff[j] - bf16_to_f32(hh));
    }
    *(short4_t*)(hi + i) = h;
    *(short4_t*)(lo + i) = l;
  } else {
    short* out = wbase + (size_t)6 * n;
    short4_t s;
#pragma unroll
    for (int j = 0; j < 4; ++j) s[j] = (short)f32_to_bf16(ff[j]);
    *(short4_t*)(out + i) = s;
  }
}

// ---------------------------------------------------------------------------
// Projection GEMM: C[M,1024] = A[M,K] @ (Bh+Bl)[1024,K]^T, 2 MFMA chains.
// Tile 128M x 64N. EPI 0: Q hi+lo head-split, PRE-SCALED by log2e.
// EPI 1: K hi head-split. EPI 2: V hi TRANSPOSED [B,H,64,S].
// ---------------------------------------------------------------------------
template <int EPI>
__global__ __launch_bounds__(256, 2) void gemm_proj(
    const short* __restrict__ A, const short* __restrict__ Bh,
    const short* __restrict__ Bl, short* __restrict__ Ohi,
    short* __restrict__ Olo, int M, int K) {
  __shared__ short As[128 * 32];
  __shared__ short Bsh[64 * 32];
  __shared__ short Bsl[64 * 32];

  const int tid = threadIdx.x;
  const int w = tid >> 6, l = tid & 63, g = l >> 4, c = l & 15;
  const int wr = w >> 1, wc = w & 1;
  const int m0 = blockIdx.y * 128, n0 = blockIdx.x * 64;

  f32x4_t acc[4][2] = {};

  for (int k0 = 0; k0 < K; k0 += 32) {
#pragma unroll
    for (int j = 0; j < 2; ++j) {
      int e = (w * 2 + j) * 512 + l * 8;
      int r = e >> 5, cc = e & 31;
      gload_lds16(A + (size_t)(m0 + r) * K + k0 + cc, &As[(w * 2 + j) * 512]);
    }
    {
      int e = w * 512 + l * 8;
      int r = e >> 5, cc = e & 31;
      gload_lds16(Bh + (size_t)(n0 + r) * K + k0 + cc, &Bsh[w * 512]);
      gload_lds16(Bl + (size_t)(n0 + r) * K + k0 + cc, &Bsl[w * 512]);
    }
    __syncthreads();

    short8_t a[4], bh[2], bl[2];
#pragma unroll
    for (int mi = 0; mi < 4; ++mi)
      a[mi] = *(const short8_t*)(&As[(wr * 64 + mi * 16 + c) * 32 + g * 8]);
#pragma unroll
    for (int ni = 0; ni < 2; ++ni) {
      bh[ni] = *(const short8_t*)(&Bsh[(wc * 32 + ni * 16 + c) * 32 + g * 8]);
      bl[ni] = *(const short8_t*)(&Bsl[(wc * 32 + ni * 16 + c) * 32 + g * 8]);
    }
#pragma unroll
    for (int mi = 0; mi < 4; ++mi)
#pragma unroll
      for (int ni = 0; ni < 2; ++ni) {
        acc[mi][ni] = __builtin_amdgcn_mfma_f32_16x16x32_bf16(
            a[mi], bh[ni], acc[mi][ni], 0, 0, 0);
        acc[mi][ni] = __builtin_amdgcn_mfma_f32_16x16x32_bf16(
            a[mi], bl[ni], acc[mi][ni], 0, 0, 0);
      }
    __syncthreads();
  }

#pragma unroll
  for (int mi = 0; mi < 4; ++mi) {
#pragma unroll
    for (int ni = 0; ni < 2; ++ni) {
      int col = n0 + wc * 32 + ni * 16 + c;
      int hh = col >> 6, dd = col & 63;
      if (EPI == 2) {
        int row0 = m0 + wr * 64 + mi * 16 + g * 4;
        int bb = row0 >> 11, ss0 = row0 & 2047;
        short4_t s4;
#pragma unroll
        for (int j = 0; j < 4; ++j) s4[j] = (short)f32_to_bf16(acc[mi][ni][j]);
        *(short4_t*)(&Ohi[(((size_t)bb * HEADS + hh) * DK + dd) * SEQ + ss0]) = s4;
      } else {
#pragma unroll
        for (int j = 0; j < 4; ++j) {
          int row = m0 + wr * 64 + mi * 16 + g * 4 + j;
          int bb = row >> 11, ss = row & 2047;
          size_t idx = (((size_t)bb * HEADS + hh) * SEQ + ss) * DK + dd;
          float x = acc[mi][ni][j];
          if (EPI == 0) x *= LOG2E;   // fold log2e into Q for exp2 softmax
          unsigned short xh = f32_to_bf16(x);
          Ohi[idx] = (short)xh;
          if (EPI == 0)
            Olo[idx] = (short)f32_to_bf16(x - bf16_to_f32(xh));
        }
      }
    }
  }
}

// ---------------------------------------------------------------------------
// Output GEMM: O[M,1024] fp32 = A[M,K] @ Bw[1024,K]^T, plain bf16, 1 chain.
// ---------------------------------------------------------------------------
__global__ __launch_bounds__(256, 2) void gemm_out(
    const short* __restrict__ A, const short* __restrict__ Bw,
    float* __restrict__ O, int M, int K) {
  __shared__ short As[128 * 32];
  __shared__ short Bs[64 * 32];

  const int tid = threadIdx.x;
  const int w = tid >> 6, l = tid & 63, g = l >> 4, c = l & 15;
  const int wr = w >> 1, wc = w & 1;
  const int m0 = blockIdx.y * 128, n0 = blockIdx.x * 64;

  f32x4_t acc[4][2] = {};

  for (int k0 = 0; k0 < K; k0 += 32) {
#pragma unroll
    for (int j = 0; j < 2; ++j) {
      int e = (w * 2 + j) * 512 + l * 8;
      int r = e >> 5, cc = e & 31;
      gload_lds16(A + (size_t)(m0 + r) * K + k0 + cc, &As[(w * 2 + j) * 512]);
    }
    {
      int e = w * 512 + l * 8;
      int r = e >> 5, cc = e & 31;
      gload_lds16(Bw + (size_t)(n0 + r) * K + k0 + cc, &Bs[w * 512]);
    }
    __syncthreads();

    short8_t a[4], b[2];
#pragma unroll
    for (int mi = 0; mi < 4; ++mi)
      a[mi] = *(const short8_t*)(&As[(wr * 64 + mi * 16 + c) * 32 + g * 8]);
#pragma unroll
    for (int ni = 0; ni < 2; ++ni)
      b[ni] = *(const short8_t*)(&Bs[(wc * 32 + ni * 16 + c) * 32 + g * 8]);
#pragma unroll
    for (int mi = 0; mi < 4; ++mi)
#pragma unroll
      for (int ni = 0; ni < 2; ++ni)
        acc[mi][ni] = __builtin_amdgcn_mfma_f32_16x16x32_bf16(
            a[mi], b[ni], acc[mi][ni], 0, 0, 0);
    __syncthreads();
  }

#pragma unroll
  for (int mi = 0; mi < 4; ++mi)
#pragma unroll
    for (int ni = 0; ni < 2; ++ni) {
      int col = n0 + wc * 32 + ni * 16 + c;
#pragma unroll
      for (int j = 0; j < 4; ++j) {
        int row = m0 + wr * 64 + mi * 16 + g * 4 + j;
        O[(size_t)row * DFF + col] = acc[mi][ni][j];
      }
    }
}

// ---------------------------------------------------------------------------
// Flash attention v10. Grid (B*H, S/128), 256 thr = 4 waves x 32 q-rows.
// Double-buffered K/V LDS, ONE barrier per chunk; staging + prefetch at TOP
// of iteration (full-cover for both the ds_write's vmcnt and the new loads).
// S^T: mfma(A=K_hi rows kv, B=Q rows q). PV: O^T = mfma(A=V^T, B=P).
// LDS map (shorts): K[2][64*76]@0, V[2][64*76]@9728, Ps[4][32*76]@19456.
// ---------------------------------------------------------------------------
__global__ __launch_bounds__(256, 2) void attn_kernel(
    const short* __restrict__ qhh, const short* __restrict__ qhl,
    const short* __restrict__ khh, const short* __restrict__ vt,
    const float* __restrict__ mask, short* __restrict__ ctx) {
  const int bh = blockIdx.x;
  const int b = bh >> 4;
  const int h = bh & 15;
  const int qt = blockIdx.y;
  const int tid = threadIdx.x;
  const int w = tid >> 6, l = tid & 63, g = l >> 4, c = l & 15;

  __shared__ short smem[29184];          // 58368 B
  short* psw = &smem[19456 + w * 2432];  // per-wave P [32][76]

  const int qrow0 = qt * 128 + w * 32;
  const short* Qbh = qhh + ((size_t)bh * SEQ + qrow0) * DK;
  const short* Qbl = qhl + ((size_t)bh * SEQ + qrow0) * DK;
  const short* Kbh = khh + (size_t)bh * SEQ * DK;
  const short* Vb  = vt  + (size_t)bh * DK * SEQ;           // [64][SEQ]
  const float* M0  = mask + (size_t)b * SEQ * SEQ + (size_t)(qrow0 + c) * SEQ;

  // staging: each thread 16 contiguous shorts per buffer
  const int srow = tid >> 2;            // 0..63
  const int scol = (tid & 3) * 16;      // 0,16,32,48
  const int sofs = srow * LSTR + scol;

  // Q frags (B-operand): lane c holds Q row q=mi*16+c, k = ks*32+g*8
  short8_t qfh[2][2], qfl[2][2];
#pragma unroll
  for (int mi = 0; mi < 2; ++mi)
#pragma unroll
    for (int ks = 0; ks < 2; ++ks) {
      qfh[mi][ks] = *(const short8_t*)(Qbh + (size_t)(mi * 16 + c) * DK + ks * 32 + g * 8);
      qfl[mi][ks] = *(const short8_t*)(Qbl + (size_t)(mi * 16 + c) * DK + ks * 32 + g * 8);
    }

  // prologue: chunk0 -> LDS buf0; chunk1 -> regs; chunk0 mask -> regs
  short8_t rk0 = *(const short8_t*)(Kbh + (size_t)srow * DK + scol);
  short8_t rk1 = *(const short8_t*)(Kbh + (size_t)srow * DK + scol + 8);
  short8_t rv0 = *(const short8_t*)(Vb + (size_t)srow * SEQ + scol);
  short8_t rv1 = *(const short8_t*)(Vb + (size_t)srow * SEQ + scol + 8);
  *(short8_t*)(&smem[sofs]) = rk0;
  *(short8_t*)(&smem[sofs + 8]) = rk1;
  *(short8_t*)(&smem[9728 + sofs]) = rv0;
  *(short8_t*)(&smem[9728 + sofs + 8]) = rv1;
  rk0 = *(const short8_t*)(Kbh + (size_t)(64 + srow) * DK + scol);
  rk1 = *(const short8_t*)(Kbh + (size_t)(64 + srow) * DK + scol + 8);
  rv0 = *(const short8_t*)(Vb + (size_t)srow * SEQ + 64 + scol);
  rv1 = *(const short8_t*)(Vb + (size_t)srow * SEQ + 64 + scol + 8);

  float4 mpre[2][4];
#pragma unroll
  for (int mi = 0; mi < 2; ++mi)
#pragma unroll
    for (int ni = 0; ni < 4; ++ni)
      mpre[mi][ni] = *(const float4*)(M0 + (size_t)(mi * 16) * SEQ + ni * 16 + g * 4);

  __syncthreads();   // buf0 visible

  f32x4_t o[4][2] = {};          // o[di][mi]: O^T rows d=di*16+g*4+j, col q
  float mrun[2] = {-1e30f, -1e30f};
  float lrun[2] = {0.f, 0.f};

  int cur = 0;
  for (int t = 0; t < 32; ++t) {
    // ---- TOP: stage chunk t+1 into buf[cur^1]; issue chunk t+2 loads ----
    // ds_write's vmcnt wait covers loads issued at top of iter t-1 (full
    // iteration); new loads drain at END-of-t barrier (full compute cover).
    if (t + 1 < 32) {
      short* Kd = &smem[(cur ^ 1) * 4864];
      short* Vd = &smem[9728 + (cur ^ 1) * 4864];
      *(short8_t*)(&Kd[sofs]) = rk0;
      *(short8_t*)(&Kd[sofs + 8]) = rk1;
      *(short8_t*)(&Vd[sofs]) = rv0;
      *(short8_t*)(&Vd[sofs + 8]) = rv1;
      if (t + 2 < 32) {
        int kvn = (t + 2) * 64;
        rk0 = *(const short8_t*)(Kbh + (size_t)(kvn + srow) * DK + scol);
        rk1 = *(const short8_t*)(Kbh + (size_t)(kvn + srow) * DK + scol + 8);
        rv0 = *(const short8_t*)(Vb + (size_t)srow * SEQ + kvn + scol);
        rv1 = *(const short8_t*)(Vb + (size_t)srow * SEQ + kvn + scol + 8);
      }
    }

    const short* Ks = &smem[cur * 4864];
    const short* Vs = &smem[9728 + cur * 4864];

    // ---- S^T = K_hi (Q_hi + Q_lo)^T : 2 chains ----
    f32x4_t sa[4][2] = {};       // sa[ni][mi]: rows kv=ni*16+g*4+j, col q
    __builtin_amdgcn_s_setprio(1);
#pragma unroll
    for (int ks = 0; ks < 2; ++ks) {
      short8_t ah[4];
#pragma unroll
      for (int ni = 0; ni < 4; ++ni)
        ah[ni] = *(const short8_t*)(&Ks[(ni * 16 + c) * LSTR + ks * 32 + g * 8]);
#pragma unroll
      for (int ni = 0; ni < 4; ++ni)
#pragma unroll
        for (int mi = 0; mi < 2; ++mi) {
          sa[ni][mi] = __builtin_amdgcn_mfma_f32_16x16x32_bf16(
              ah[ni], qfh[mi][ks], sa[ni][mi], 0, 0, 0);
          sa[ni][mi] = __builtin_amdgcn_mfma_f32_16x16x32_bf16(
              ah[ni], qfl[mi][ks], sa[ni][mi], 0, 0, 0);
        }
    }
    __builtin_amdgcn_s_setprio(0);

    // ---- + mask * log2e from prefetched regs; then prefetch t+1 ----
#pragma unroll
    for (int mi = 0; mi < 2; ++mi)
#pragma unroll
      for (int ni = 0; ni < 4; ++ni) {
        sa[ni][mi][0] = fmaf(mpre[mi][ni].x, LOG2E, sa[ni][mi][0]);
        sa[ni][mi][1] = fmaf(mpre[mi][ni].y, LOG2E, sa[ni][mi][1]);
        sa[ni][mi][2] = fmaf(mpre[mi][ni].z, LOG2E, sa[ni][mi][2]);
        sa[ni][mi][3] = fmaf(mpre[mi][ni].w, LOG2E, sa[ni][mi][3]);
      }
    if (t + 1 < 32) {
      int kvn = (t + 1) * 64;
#pragma unroll
      for (int mi = 0; mi < 2; ++mi)
#pragma unroll
        for (int ni = 0; ni < 4; ++ni)
          mpre[mi][ni] = *(const float4*)(M0 + (size_t)(mi * 16) * SEQ + kvn + ni * 16 + g * 4);
    }

    // ---- online softmax (log2 space), defer-max THR=8, per mi ----
#pragma unroll
    for (int mi = 0; mi < 2; ++mi) {
      float tmx = sa[0][mi][0];
#pragma unroll
      for (int ni = 0; ni < 4; ++ni)
#pragma unroll
        for (int j = 0; j < 4; ++j) tmx = fmaxf(tmx, sa[ni][mi][j]);
      tmx = fmaxf(tmx, __shfl_xor(tmx, 16));
      tmx = fmaxf(tmx, __shfl_xor(tmx, 32));
      if (!__all(tmx - mrun[mi] <= 8.f)) {
        float mnew = fmaxf(mrun[mi], tmx);
        float sc = fexp2(mrun[mi] - mnew);
        mrun[mi] = mnew;
        lrun[mi] *= sc;
#pragma unroll
        for (int di = 0; di < 4; ++di)
#pragma unroll
          for (int j = 0; j < 4; ++j) o[di][mi][j] *= sc;
      }
      float psum = 0.f;
#pragma unroll
      for (int ni = 0; ni < 4; ++ni) {
        float p0 = fexp2(sa[ni][mi][0] - mrun[mi]);
        float p1 = fexp2(sa[ni][mi][1] - mrun[mi]);
        float p2 = fexp2(sa[ni][mi][2] - mrun[mi]);
        float p3 = fexp2(sa[ni][mi][3] - mrun[mi]);
        psum += (p0 + p1) + (p2 + p3);
        unsigned int u0 = cvt_pk_bf16(p0, p1);
        unsigned int u1 = cvt_pk_bf16(p2, p3);
        unsigned long long pu = ((unsigned long long)u1 << 32) | u0;
        *(unsigned long long*)(&psw[(mi * 16 + c) * LSTR + ni * 16 + g * 4]) = pu;
      }
      lrun[mi] += psum;
    }

    // ---- O^T += V^T P^T ----
    __builtin_amdgcn_s_setprio(1);
#pragma unroll
    for (int ks = 0; ks < 2; ++ks) {
      short8_t pb[2];
#pragma unroll
      for (int mi = 0; mi < 2; ++mi)
        pb[mi] = *(const short8_t*)(&psw[(mi * 16 + c) * LSTR + ks * 32 + g * 8]);
#pragma unroll
      for (int di = 0; di < 4; ++di) {
        short8_t av = *(const short8_t*)(&Vs[(di * 16 + c) * LSTR + ks * 32 + g * 8]);
#pragma unroll
        for (int mi = 0; mi < 2; ++mi)
          o[di][mi] = __builtin_amdgcn_mfma_f32_16x16x32_bf16(
              av, pb[mi], o[di][mi], 0, 0, 0);
      }
    }
    __builtin_amdgcn_s_setprio(0);

    __syncthreads();   // buf[cur^1] ready; all reads of buf[cur] done
    cur ^= 1;
  }

  // ---- finalize: reduce l across g-groups, normalize, short4 stores ----
  float inv[2];
#pragma unroll
  for (int mi = 0; mi < 2; ++mi) {
    float s = lrun[mi];
    s += __shfl_xor(s, 16);
    s += __shfl_xor(s, 32);
    inv[mi] = 1.f / s;
  }
  short* Cb = ctx + ((size_t)b * SEQ + qrow0) * DFF + h * DK;
#pragma unroll
  for (int mi = 0; mi < 2; ++mi)
#pragma unroll
    for (int di = 0; di < 4; ++di) {
      short4_t s4;
#pragma unroll
      for (int j = 0; j < 4; ++j)
        s4[j] = (short)f32_to_bf16(o[di][mi][j] * inv[mi]);
      *(short4_t*)(Cb + (size_t)(mi * 16 + c) * DFF + di * 16 + g * 4) = s4;
    }
}

// ---------------------------------------------------------------------------
extern "C" void kernel_launch(void* const* d_in, const int* in_sizes, int n_in,
                              void* d_out, int out_size, void* d_ws, size_t ws_size,
                              hipStream_t stream) {
  const float* q    = (const float*)d_in[0];
  const float* k    = (const float*)d_in[1];
  const float* v    = (const float*)d_in[2];
  const float* mask = (const float*)d_in[3];
  const float* Wq   = (const float*)d_in[4];
  const float* Wk   = (const float*)d_in[5];
  const float* Wv   = (const float*)d_in[6];
  const float* Wo   = (const float*)d_in[7];
  float* out = (float*)d_out;

  const size_t NQ = 4194304;   // 4096*1024
  const size_t NW = 1048576;   // 1024*1024
  short* ws   = (short*)d_ws;
  short* qbf  = ws;            // A0; reused as kh_h after Q-proj
  short* kbf  = ws + NQ;       // A1; reused as vtp after K-proj
  short* vbf  = ws + 2 * NQ;   // A2; reused as ctx after V-proj
  short* qh_h = ws + 3 * NQ;
  short* qh_l = ws + 4 * NQ;
  short* wbase = ws + 5 * NQ;  // [wq_h wq_l wk_h wk_l wv_h wv_l wob], NW each
  short* wq_h = wbase;
  short* wq_l = wbase + NW;
  short* wk_h = wbase + 2 * NW;
  short* wk_l = wbase + 3 * NW;
  short* wv_h = wbase + 4 * NW;
  short* wv_l = wbase + 5 * NW;
  short* wob  = wbase + 6 * NW;   // total 5*NQ + 7*NW = 56.6 MB

  short* kh_h = qbf;   // aliases (stream-ordered, safe)
  short* vtp  = kbf;   // V transposed [B,H,64,S]
  short* ctx  = vbf;

  cvt_x_kernel<<<dim3(4096, 3), 256, 0, stream>>>(q, k, v, ws, (int)NQ);
  cvt_w_kernel<<<dim3(1024, 4), 256, 0, stream>>>(Wq, Wk, Wv, Wo, wbase, (int)NW);

  dim3 gg(16, 32);   // N/64, M/128
  gemm_proj<0><<<gg, 256, 0, stream>>>(qbf, wq_h, wq_l, qh_h, qh_l, 4096, 1024);
  gemm_proj<1><<<gg, 256, 0, stream>>>(kbf, wk_h, wk_l, kh_h, nullptr, 4096, 1024);
  gemm_proj<2><<<gg, 256, 0, stream>>>(vbf, wv_h, wv_l, vtp, nullptr, 4096, 1024);

  attn_kernel<<<dim3(32, 16), 256, 0, stream>>>(qh_h, qh_l, kh_h, vtp, mask, ctx);

  gemm_out<<<gg, 256, 0, stream>>>(ctx, wob, out, 4096, 1024);
}

// Round 13
// 208.545 us; speedup vs baseline: 1.4804x; 1.4775x over previous
//
#include <hip/hip_runtime.h>
#include <hip/hip_bf16.h>

// ---------------------------------------------------------------------------
// T5 MHA: B=2, S=2048, D_FF=1024, H=16, DK=64, INNER=1024
// Precision: q carried hi+lo (2-chain QK vs k_hi); W's split for projections.
// Attn v11 = R10's v8 (proven: 512 thr, 8 waves x 16 q-rows, 2 barriers,
// stride-76 LDS = 0 conflicts, VGPR 56 no-spill) with ONE change:
// libm exp2f -> __builtin_amdgcn_exp2f (raw v_exp_f32). R10's +12us VALU
// regression was the libm call. Defer-max + cvt_pk + mask prefetch kept.
// R11/R12 lesson: single-barrier dbuf collapses under compiler rescheduling
// at 2 waves/SIMD -- abandoned.
// ---------------------------------------------------------------------------

typedef __attribute__((ext_vector_type(8))) short short8_t;   // 8 bf16 (4 VGPR)
typedef __attribute__((ext_vector_type(4))) short short4_t;
typedef __attribute__((ext_vector_type(4))) float f32x4_t;

#define SEQ 2048
#define HEADS 16
#define DK 64
#define DFF 1024
#define LOG2E 1.44269504088896340736f
#define LSTR 76   // LDS row stride (bf16): 38 dwords == 6 mod 32 banks

__device__ __forceinline__ unsigned short f32_to_bf16(float f) {
  unsigned int u = __float_as_uint(f);
  u += 0x7FFFu + ((u >> 16) & 1u);   // round-to-nearest-even
  return (unsigned short)(u >> 16);
}
__device__ __forceinline__ float bf16_to_f32(unsigned short h) {
  return __uint_as_float(((unsigned int)h) << 16);
}
__device__ __forceinline__ unsigned int cvt_pk_bf16(float a, float b) {
  unsigned int r;
  asm("v_cvt_pk_bf16_f32 %0, %1, %2" : "=v"(r) : "v"(a), "v"(b));
  return r;
}
__device__ __forceinline__ float fexp2(float x) {
  return __builtin_amdgcn_exp2f(x);   // raw v_exp_f32 (2^x), no libm fixup
}

__device__ __forceinline__ void gload_lds16(const void* g, void* l) {
  __builtin_amdgcn_global_load_lds(
      (__attribute__((address_space(1))) void*)(g),
      (__attribute__((address_space(3))) void*)(l), 16, 0, 0);
}

// ---------------------------------------------------------------------------
// cvt_x: q/k/v fp32 -> bf16, one dispatch
// ---------------------------------------------------------------------------
__global__ void cvt_x_kernel(const float* __restrict__ q,
                             const float* __restrict__ k,
                             const float* __restrict__ v,
                             short* __restrict__ dst, int n) {
  const float* src = (blockIdx.y == 0) ? q : (blockIdx.y == 1) ? k : v;
  short* out = dst + (size_t)blockIdx.y * n;
  int i = (blockIdx.x * 256 + threadIdx.x) * 4;
  if (i >= n) return;
  float4 f = *(const float4*)(src + i);
  short4_t s;
  s[0] = (short)f32_to_bf16(f.x);
  s[1] = (short)f32_to_bf16(f.y);
  s[2] = (short)f32_to_bf16(f.z);
  s[3] = (short)f32_to_bf16(f.w);
  *(short4_t*)(out + i) = s;
}

// ---------------------------------------------------------------------------
// cvt_w: y<3 -> split W[y] into hi+lo pair; y==3 -> plain Wo
// ---------------------------------------------------------------------------
__global__ void cvt_w_kernel(const float* __restrict__ Wq,
                             const float* __restrict__ Wk,
                             const float* __restrict__ Wv,
                             const float* __restrict__ Wo,
                             short* __restrict__ wbase, int n) {
  int y = blockIdx.y;
  const float* src = (y == 0) ? Wq : (y == 1) ? Wk : (y == 2) ? Wv : Wo;
  int i = (blockIdx.x * 256 + threadIdx.x) * 4;
  if (i >= n) return;
  float4 f = *(const float4*)(src + i);
  float ff[4] = {f.x, f.y, f.z, f.w};
  if (y < 3) {
    short* hi = wbase + (size_t)(2 * y) * n;
    short* lo = wbase + (size_t)(2 * y + 1) * n;
    short4_t h, l;
#pragma unroll
    for (int j = 0; j < 4; ++j) {
      unsigned short hh = f32_to_bf16(ff[j]);
      h[j] = (short)hh;
      l[j] = (short)f32_to_bf16(ff[j] - bf16_to_f32(hh));
    }
    *(short4_t*)(hi + i) = h;
    *(short4_t*)(lo + i) = l;
  } else {
    short* out = wbase + (size_t)6 * n;
    short4_t s;
#pragma unroll
    for (int j = 0; j < 4; ++j) s[j] = (short)f32_to_bf16(ff[j]);
    *(short4_t*)(out + i) = s;
  }
}

// ---------------------------------------------------------------------------
// Projection GEMM: C[M,1024] = A[M,K] @ (Bh+Bl)[1024,K]^T, 2 MFMA chains.
// Tile 128M x 64N. EPI 0: Q hi+lo head-split, PRE-SCALED by log2e.
// EPI 1: K hi head-split. EPI 2: V hi TRANSPOSED [B,H,64,S].
// ---------------------------------------------------------------------------
template <int EPI>
__global__ __launch_bounds__(256, 2) void gemm_proj(
    const short* __restrict__ A, const short* __restrict__ Bh,
    const short* __restrict__ Bl, short* __restrict__ Ohi,
    short* __restrict__ Olo, int M, int K) {
  __shared__ short As[128 * 32];
  __shared__ short Bsh[64 * 32];
  __shared__ short Bsl[64 * 32];

  const int tid = threadIdx.x;
  const int w = tid >> 6, l = tid & 63, g = l >> 4, c = l & 15;
  const int wr = w >> 1, wc = w & 1;
  const int m0 = blockIdx.y * 128, n0 = blockIdx.x * 64;

  f32x4_t acc[4][2] = {};

  for (int k0 = 0; k0 < K; k0 += 32) {
#pragma unroll
    for (int j = 0; j < 2; ++j) {
      int e = (w * 2 + j) * 512 + l * 8;
      int r = e >> 5, cc = e & 31;
      gload_lds16(A + (size_t)(m0 + r) * K + k0 + cc, &As[(w * 2 + j) * 512]);
    }
    {
      int e = w * 512 + l * 8;
      int r = e >> 5, cc = e & 31;
      gload_lds16(Bh + (size_t)(n0 + r) * K + k0 + cc, &Bsh[w * 512]);
      gload_lds16(Bl + (size_t)(n0 + r) * K + k0 + cc, &Bsl[w * 512]);
    }
    __syncthreads();

    short8_t a[4], bh[2], bl[2];
#pragma unroll
    for (int mi = 0; mi < 4; ++mi)
      a[mi] = *(const short8_t*)(&As[(wr * 64 + mi * 16 + c) * 32 + g * 8]);
#pragma unroll
    for (int ni = 0; ni < 2; ++ni) {
      bh[ni] = *(const short8_t*)(&Bsh[(wc * 32 + ni * 16 + c) * 32 + g * 8]);
      bl[ni] = *(const short8_t*)(&Bsl[(wc * 32 + ni * 16 + c) * 32 + g * 8]);
    }
#pragma unroll
    for (int mi = 0; mi < 4; ++mi)
#pragma unroll
      for (int ni = 0; ni < 2; ++ni) {
        acc[mi][ni] = __builtin_amdgcn_mfma_f32_16x16x32_bf16(
            a[mi], bh[ni], acc[mi][ni], 0, 0, 0);
        acc[mi][ni] = __builtin_amdgcn_mfma_f32_16x16x32_bf16(
            a[mi], bl[ni], acc[mi][ni], 0, 0, 0);
      }
    __syncthreads();
  }

#pragma unroll
  for (int mi = 0; mi < 4; ++mi) {
#pragma unroll
    for (int ni = 0; ni < 2; ++ni) {
      int col = n0 + wc * 32 + ni * 16 + c;
      int hh = col >> 6, dd = col & 63;
      if (EPI == 2) {
        int row0 = m0 + wr * 64 + mi * 16 + g * 4;
        int bb = row0 >> 11, ss0 = row0 & 2047;
        short4_t s4;
#pragma unroll
        for (int j = 0; j < 4; ++j) s4[j] = (short)f32_to_bf16(acc[mi][ni][j]);
        *(short4_t*)(&Ohi[(((size_t)bb * HEADS + hh) * DK + dd) * SEQ + ss0]) = s4;
      } else {
#pragma unroll
        for (int j = 0; j < 4; ++j) {
          int row = m0 + wr * 64 + mi * 16 + g * 4 + j;
          int bb = row >> 11, ss = row & 2047;
          size_t idx = (((size_t)bb * HEADS + hh) * SEQ + ss) * DK + dd;
          float x = acc[mi][ni][j];
          if (EPI == 0) x *= LOG2E;   // fold log2e into Q for exp2 softmax
          unsigned short xh = f32_to_bf16(x);
          Ohi[idx] = (short)xh;
          if (EPI == 0)
            Olo[idx] = (short)f32_to_bf16(x - bf16_to_f32(xh));
        }
      }
    }
  }
}

// ---------------------------------------------------------------------------
// Output GEMM: O[M,1024] fp32 = A[M,K] @ Bw[1024,K]^T, plain bf16, 1 chain.
// ---------------------------------------------------------------------------
__global__ __launch_bounds__(256, 2) void gemm_out(
    const short* __restrict__ A, const short* __restrict__ Bw,
    float* __restrict__ O, int M, int K) {
  __shared__ short As[128 * 32];
  __shared__ short Bs[64 * 32];

  const int tid = threadIdx.x;
  const int w = tid >> 6, l = tid & 63, g = l >> 4, c = l & 15;
  const int wr = w >> 1, wc = w & 1;
  const int m0 = blockIdx.y * 128, n0 = blockIdx.x * 64;

  f32x4_t acc[4][2] = {};

  for (int k0 = 0; k0 < K; k0 += 32) {
#pragma unroll
    for (int j = 0; j < 2; ++j) {
      int e = (w * 2 + j) * 512 + l * 8;
      int r = e >> 5, cc = e & 31;
      gload_lds16(A + (size_t)(m0 + r) * K + k0 + cc, &As[(w * 2 + j) * 512]);
    }
    {
      int e = w * 512 + l * 8;
      int r = e >> 5, cc = e & 31;
      gload_lds16(Bw + (size_t)(n0 + r) * K + k0 + cc, &Bs[w * 512]);
    }
    __syncthreads();

    short8_t a[4], b[2];
#pragma unroll
    for (int mi = 0; mi < 4; ++mi)
      a[mi] = *(const short8_t*)(&As[(wr * 64 + mi * 16 + c) * 32 + g * 8]);
#pragma unroll
    for (int ni = 0; ni < 2; ++ni)
      b[ni] = *(const short8_t*)(&Bs[(wc * 32 + ni * 16 + c) * 32 + g * 8]);
#pragma unroll
    for (int mi = 0; mi < 4; ++mi)
#pragma unroll
      for (int ni = 0; ni < 2; ++ni)
        acc[mi][ni] = __builtin_amdgcn_mfma_f32_16x16x32_bf16(
            a[mi], b[ni], acc[mi][ni], 0, 0, 0);
    __syncthreads();
  }

#pragma unroll
  for (int mi = 0; mi < 4; ++mi)
#pragma unroll
    for (int ni = 0; ni < 2; ++ni) {
      int col = n0 + wc * 32 + ni * 16 + c;
#pragma unroll
      for (int j = 0; j < 4; ++j) {
        int row = m0 + wr * 64 + mi * 16 + g * 4 + j;
        O[(size_t)row * DFF + col] = acc[mi][ni][j];
      }
    }
}

// ---------------------------------------------------------------------------
// Flash attention v11. Grid (B*H, S/128), 512 thr = 8 waves x 16 q-rows.
// 2 blocks/CU -> 4 waves/SIMD. S^T: mfma(A=K_hi rows kv, B=Q rows q).
// PV: O^T = mfma(A=V^T rows d, B=P rows q). K_hi + V^T staged in LDS
// (stride 76: 0 conflicts); issue-early K/V prefetch; mask reg prefetch;
// exp2 softmax (raw v_exp_f32) with defer-max; cvt_pk P-pack.
// ---------------------------------------------------------------------------
__global__ __launch_bounds__(512, 4) void attn_kernel(
    const short* __restrict__ qhh, const short* __restrict__ qhl,
    const short* __restrict__ khh, const short* __restrict__ vt,
    const float* __restrict__ mask, short* __restrict__ ctx) {
  const int bh = blockIdx.x;
  const int b = bh >> 4;
  const int h = bh & 15;
  const int qt = blockIdx.y;
  const int tid = threadIdx.x;
  const int w = tid >> 6, l = tid & 63, g = l >> 4, c = l & 15;

  __shared__ short Khs[64 * LSTR];      // K chunk hi [kv][k]
  __shared__ short Vts[64 * LSTR];      // V^T chunk [d][kv]
  __shared__ short Ps[8][16 * LSTR];    // per-wave P tile [q=16][kv]
  short* psw = &Ps[w][0];

  const int qrow0 = qt * 128 + w * 16;
  const short* Qbh = qhh + ((size_t)bh * SEQ + qrow0) * DK;
  const short* Qbl = qhl + ((size_t)bh * SEQ + qrow0) * DK;
  const short* Kbh = khh + (size_t)bh * SEQ * DK;
  const short* Vb  = vt  + (size_t)bh * DK * SEQ;           // [64][SEQ]
  const float* M0  = mask + (size_t)b * SEQ * SEQ + (size_t)(qrow0 + c) * SEQ;

  // staging: 512 threads x 1 short8 per buffer = full 64x64 coverage
  const int srow = tid >> 3;            // 0..63
  const int scol = (tid & 7) * 8;       // 0..56
  const int sofs = srow * LSTR + scol;

  // Q frags (B-operand): lane c holds Q row q=c, k = ks*32+g*8
  short8_t qfh[2], qfl[2];
#pragma unroll
  for (int ks = 0; ks < 2; ++ks) {
    qfh[ks] = *(const short8_t*)(Qbh + (size_t)c * DK + ks * 32 + g * 8);
    qfl[ks] = *(const short8_t*)(Qbl + (size_t)c * DK + ks * 32 + g * 8);
  }

  // prologue: chunk-0 staging regs + chunk-0 mask regs
  short8_t rkh = *(const short8_t*)(Kbh + (size_t)srow * DK + scol);
  short8_t rv  = *(const short8_t*)(Vb  + (size_t)srow * SEQ + scol);
  float4 mpre[4];
#pragma unroll
  for (int ni = 0; ni < 4; ++ni)
    mpre[ni] = *(const float4*)(M0 + ni * 16 + g * 4);

  f32x4_t o[4] = {};             // o[di]: O^T rows d=di*16+g*4+j, col q=c
  float mrun = -1e30f;
  float lrun = 0.f;

  for (int kv0 = 0; kv0 < SEQ; kv0 += 64) {
    __syncthreads();             // prev iter's readers done
    *(short8_t*)(&Khs[sofs]) = rkh;
    *(short8_t*)(&Vts[sofs]) = rv;
    __syncthreads();             // staged data visible to all waves

    const int kv1 = kv0 + 64;
    // issue-early: next chunk's K/V loads overlap this iteration's compute
    if (kv1 < SEQ) {
      rkh = *(const short8_t*)(Kbh + (size_t)(kv1 + srow) * DK + scol);
      rv  = *(const short8_t*)(Vb  + (size_t)srow * SEQ + kv1 + scol);
    }

    // ---- S^T = K_hi (Q_hi + Q_lo)^T : 2 chains, K frags from LDS ----
    f32x4_t sa[4] = {};          // sa[ni]: rows kv=ni*16+g*4+j, col q=c
    __builtin_amdgcn_s_setprio(1);
#pragma unroll
    for (int ks = 0; ks < 2; ++ks) {
#pragma unroll
      for (int ni = 0; ni < 4; ++ni) {
        short8_t ah = *(const short8_t*)(&Khs[(ni * 16 + c) * LSTR + ks * 32 + g * 8]);
        sa[ni] = __builtin_amdgcn_mfma_f32_16x16x32_bf16(
            ah, qfh[ks], sa[ni], 0, 0, 0);
        sa[ni] = __builtin_amdgcn_mfma_f32_16x16x32_bf16(
            ah, qfl[ks], sa[ni], 0, 0, 0);
      }
    }
    __builtin_amdgcn_s_setprio(0);

    // ---- + mask * log2e from prefetched regs; then prefetch t+1 ----
#pragma unroll
    for (int ni = 0; ni < 4; ++ni) {
      sa[ni][0] = fmaf(mpre[ni].x, LOG2E, sa[ni][0]);
      sa[ni][1] = fmaf(mpre[ni].y, LOG2E, sa[ni][1]);
      sa[ni][2] = fmaf(mpre[ni].z, LOG2E, sa[ni][2]);
      sa[ni][3] = fmaf(mpre[ni].w, LOG2E, sa[ni][3]);
    }
    if (kv1 < SEQ) {
#pragma unroll
      for (int ni = 0; ni < 4; ++ni)
        mpre[ni] = *(const float4*)(M0 + kv1 + ni * 16 + g * 4);
    }

    // ---- online softmax (log2 space), defer-max THR=8 ----
    {
      float t = sa[0][0];
#pragma unroll
      for (int ni = 0; ni < 4; ++ni)
#pragma unroll
        for (int j = 0; j < 4; ++j) t = fmaxf(t, sa[ni][j]);
      t = fmaxf(t, __shfl_xor(t, 16));
      t = fmaxf(t, __shfl_xor(t, 32));
      if (!__all(t - mrun <= 8.f)) {
        float mnew = fmaxf(mrun, t);
        float sc = fexp2(mrun - mnew);
        mrun = mnew;
        lrun *= sc;
#pragma unroll
        for (int di = 0; di < 4; ++di)
#pragma unroll
          for (int j = 0; j < 4; ++j) o[di][j] *= sc;
      }
      float psum = 0.f;
#pragma unroll
      for (int ni = 0; ni < 4; ++ni) {
        float p0 = fexp2(sa[ni][0] - mrun);
        float p1 = fexp2(sa[ni][1] - mrun);
        float p2 = fexp2(sa[ni][2] - mrun);
        float p3 = fexp2(sa[ni][3] - mrun);
        psum += (p0 + p1) + (p2 + p3);
        unsigned int u0 = cvt_pk_bf16(p0, p1);
        unsigned int u1 = cvt_pk_bf16(p2, p3);
        unsigned long long pu = ((unsigned long long)u1 << 32) | u0;
        // P store: [q][kv] A-layout, b64, ~2-way max at stride 76
        *(unsigned long long*)(&psw[c * LSTR + ni * 16 + g * 4]) = pu;
      }
      lrun += psum;
    }

    // ---- O^T += V^T P^T : V frags from LDS ----
    __builtin_amdgcn_s_setprio(1);
#pragma unroll
    for (int ks = 0; ks < 2; ++ks) {
      short8_t pb = *(const short8_t*)(&psw[c * LSTR + ks * 32 + g * 8]);
#pragma unroll
      for (int di = 0; di < 4; ++di) {
        short8_t av = *(const short8_t*)(&Vts[(di * 16 + c) * LSTR + ks * 32 + g * 8]);
        o[di] = __builtin_amdgcn_mfma_f32_16x16x32_bf16(
            av, pb, o[di], 0, 0, 0);
      }
    }
    __builtin_amdgcn_s_setprio(0);
  }

  // ---- finalize: reduce l across g-groups, normalize, short4 stores ----
  float s = lrun;
  s += __shfl_xor(s, 16);
  s += __shfl_xor(s, 32);
  float inv = 1.f / s;
  short* Cb = ctx + ((size_t)b * SEQ + qrow0) * DFF + h * DK;
#pragma unroll
  for (int di = 0; di < 4; ++di) {
    short4_t s4;
#pragma unroll
    for (int j = 0; j < 4; ++j)
      s4[j] = (short)f32_to_bf16(o[di][j] * inv);
    *(short4_t*)(Cb + (size_t)c * DFF + di * 16 + g * 4) = s4;
  }
}

// ---------------------------------------------------------------------------
extern "C" void kernel_launch(void* const* d_in, const int* in_sizes, int n_in,
                              void* d_out, int out_size, void* d_ws, size_t ws_size,
                              hipStream_t stream) {
  const float* q    = (const float*)d_in[0];
  const float* k    = (const float*)d_in[1];
  const float* v    = (const float*)d_in[2];
  const float* mask = (const float*)d_in[3];
  const float* Wq   = (const float*)d_in[4];
  const float* Wk   = (const float*)d_in[5];
  const float* Wv   = (const float*)d_in[6];
  const float* Wo   = (const float*)d_in[7];
  float* out = (float*)d_out;

  const size_t NQ = 4194304;   // 4096*1024
  const size_t NW = 1048576;   // 1024*1024
  short* ws   = (short*)d_ws;
  short* qbf  = ws;            // A0; reused as kh_h after Q-proj
  short* kbf  = ws + NQ;       // A1; reused as vtp after K-proj
  short* vbf  = ws + 2 * NQ;   // A2; reused as ctx after V-proj
  short* qh_h = ws + 3 * NQ;
  short* qh_l = ws + 4 * NQ;
  short* wbase = ws + 5 * NQ;  // [wq_h wq_l wk_h wk_l wv_h wv_l wob], NW each
  short* wq_h = wbase;
  short* wq_l = wbase + NW;
  short* wk_h = wbase + 2 * NW;
  short* wk_l = wbase + 3 * NW;
  short* wv_h = wbase + 4 * NW;
  short* wv_l = wbase + 5 * NW;
  short* wob  = wbase + 6 * NW;   // total 5*NQ + 7*NW = 56.6 MB

  short* kh_h = qbf;   // aliases (stream-ordered, safe)
  short* vtp  = kbf;   // V transposed [B,H,64,S]
  short* ctx  = vbf;

  cvt_x_kernel<<<dim3(4096, 3), 256, 0, stream>>>(q, k, v, ws, (int)NQ);
  cvt_w_kernel<<<dim3(1024, 4), 256, 0, stream>>>(Wq, Wk, Wv, Wo, wbase, (int)NW);

  dim3 gg(16, 32);   // N/64, M/128
  gemm_proj<0><<<gg, 256, 0, stream>>>(qbf, wq_h, wq_l, qh_h, qh_l, 4096, 1024);
  gemm_proj<1><<<gg, 256, 0, stream>>>(kbf, wk_h, wk_l, kh_h, nullptr, 4096, 1024);
  gemm_proj<2><<<gg, 256, 0, stream>>>(vbf, wv_h, wv_l, vtp, nullptr, 4096, 1024);

  attn_kernel<<<dim3(32, 16), 512, 0, stream>>>(qh_h, qh_l, kh_h, vtp, mask, ctx);

  gemm_out<<<gg, 256, 0, stream>>>(ctx, wob, out, 4096, 1024);
}